// Round 9
// baseline (103.679 us; speedup 1.0000x reference)
//
#include <hip/hip_runtime.h>

// ---------------------------------------------------------------------------
// GCNN Double-Q critic, MI355X (gfx950) — round 9.
// Structure: A symmetric => transpose-free MFMA chain (D-frag == next A-frag).
// Round 9: both nets per wave (setup dedup: RAW/adjacency/x/z0 computed once
// per batch, reused for Q1+Q2). Both nets' W1 bf16-RN fragments in LDS (64KB).
// Layer 2: z split hi+lo x single-bf16 W (round 8 precision).
// ---------------------------------------------------------------------------

typedef short    s16x8 __attribute__((ext_vector_type(8)));
typedef float    f32x4 __attribute__((ext_vector_type(4)));
typedef unsigned u32x4 __attribute__((ext_vector_type(4)));

#define MFMA32(a, b, c) __builtin_amdgcn_mfma_f32_16x16x32_bf16((a), (b), (c), 0, 0, 0)

// d_ws layout (units: shorts)
constexpr int WS_W0F = 0;       // [net][t=8][lane=64][8] : {h0..h3,l0..l3}
constexpr int WS_W1  = 8192;    // [net][q=4][t=8][lane=64][8] bf16 RN

// dynamic LDS: [0,64KB) W1 frags (both nets), [64KB,+6.4KB) RAW
constexpr int LDS_RAW    = 65536;
constexpr int SMEM_TOTAL = 65536 + 8 * 200 * 4;  // 71936

__device__ __forceinline__ unsigned short bf16_rn(float f) {
  unsigned u = __float_as_uint(f);
  u = u + 0x7FFFu + ((u >> 16) & 1u);
  return (unsigned short)(u >> 16);
}
__device__ __forceinline__ void split2(float f, unsigned short& h, unsigned short& l) {
  h = bf16_rn(f);
  float fh = __uint_as_float(((unsigned)h) << 16);
  l = bf16_rn(f - fh);
}
// Packed split of a pair: H = {bf16_rhu(f1), bf16_rhu(f0)}, L = truncated
// residuals. 8 VALU per pair.
__device__ __forceinline__ void split_pk(float f0, float f1,
                                         unsigned& H, unsigned& L) {
  unsigned u0 = __float_as_uint(f0) + 0x8000u;
  unsigned u1 = __float_as_uint(f1) + 0x8000u;
  H = __builtin_amdgcn_perm(u1, u0, 0x07060302u);
  float r0 = f0 - __uint_as_float(u0 & 0xFFFF0000u);
  float r1 = f1 - __uint_as_float(u1 & 0xFFFF0000u);
  L = __builtin_amdgcn_perm(__float_as_uint(r1), __float_as_uint(r0), 0x07060302u);
}
__device__ __forceinline__ s16x8 as_s16x8(u32x4 v) {
  return __builtin_bit_cast(s16x8, v);
}

// ---------------------------- prep kernel ----------------------------------
extern "C" __global__ void __launch_bounds__(256)
prep_weights(const float* __restrict__ w0a, const float* __restrict__ w1a,
             const float* __restrict__ w0b, const float* __restrict__ w1b,
             unsigned short* __restrict__ ws) {
  const int tid = threadIdx.x;
  if (blockIdx.x < 16) {
    // W1 fragments (single bf16 RN): one 8-elem frag per thread.
    int f = blockIdx.x * 256 + tid;          // 0..4095
    int lane = f & 63, t = (f >> 6) & 7, q = (f >> 9) & 3, net = f >> 11;
    const float* W1 = net ? w1b : w1a;
    int c = 16 * t + (lane & 15);
    int kbase = 32 * q + 4 * (lane >> 4);
    s16x8 v;
#pragma unroll
    for (int e = 0; e < 8; ++e) {
      int k = kbase + (e & 3) + 16 * (e >> 2);
      v[e] = (short)bf16_rn(W1[k * 128 + c]);
    }
    ((s16x8*)(ws + WS_W1))[((net * 4 + q) * 8 + t) * 64 + lane] = v;
  } else {
    // W0 fragments hi/lo (K padded 10->16 with zeros): 1024 frags, 4/thread
#pragma unroll
    for (int i = 0; i < 4; ++i) {
      int f = i * 256 + tid;                 // 0..1023
      int lane = f & 63, t = (f >> 6) & 7, net = (f >> 9) & 1;
      const float* W0 = net ? w0b : w0a;
      int c = 16 * t + (lane & 15);
      int kbase = 4 * (lane >> 4);
      s16x8 v;
#pragma unroll
      for (int j = 0; j < 4; ++j) {
        int k = kbase + j;
        float w = (k < 10) ? W0[k * 128 + c] : 0.f;
        unsigned short h, l; split2(w, h, l);
        v[j] = (short)h; v[4 + j] = (short)l;
      }
      ((s16x8*)(ws + WS_W0F))[(net * 8 + t) * 64 + lane] = v;
    }
  }
}

// ---------------------------- main kernel ----------------------------------
extern "C" __global__ void __launch_bounds__(512, 4)
gcnn_critic_kernel(const float* __restrict__ obs, const float* __restrict__ act,
                   const float* __restrict__ b0a, const float* __restrict__ b1a,
                   const float* __restrict__ w2a, const float* __restrict__ b2a,
                   const float* __restrict__ b0b, const float* __restrict__ b1b,
                   const float* __restrict__ w2b, const float* __restrict__ b2b,
                   const unsigned short* __restrict__ ws,
                   float* __restrict__ out) {
  extern __shared__ char smem[];
  const int tid  = threadIdx.x;
  const int lane = tid & 63;
  const int wv   = tid >> 6;
  const int l15  = lane & 15;
  const int lg   = lane >> 4;
  const int batch = blockIdx.x * 8 + wv;  // one batch per wave, both nets

  s16x8* lW = (s16x8*)smem;                  // 4096 fragments (64KB)
  float* raw = (float*)(smem + LDS_RAW) + wv * 200;

  // ---- cooperative stage: BOTH nets' W1 fragments into LDS (64KB) ----
  {
    const s16x8* gW = (const s16x8*)(ws + WS_W1);
#pragma unroll
    for (int k = 0; k < 8; ++k) lW[tid + k * 512] = gW[tid + k * 512];
  }
  // stage raw features: [0..159]=obs row, [160..191]=action row
#pragma unroll
  for (int i = 0; i < 3; ++i) {
    int j = i * 64 + lane;
    if (j < 192) {
      float v = (j < 160) ? obs[batch * 160 + j] : act[batch * 32 + (j - 160)];
      raw[j] = v;
    }
  }
  __syncthreads();

  // --- adjacency (per-lane): Af[j] = A[d=l15][s=4lg+j] ; symmetric ---
  float wreg[4];
  float wsum = 0.f;
#pragma unroll
  for (int j = 0; j < 4; ++j) {
    int s = 4 * lg + j;
    float dx = raw[l15 * 10]     - raw[s * 10];
    float dy = raw[l15 * 10 + 1] - raw[s * 10 + 1];
    float w = expf(-sqrtf(dx * dx + dy * dy));
    wreg[j] = w;
    wsum += w;
  }
  wsum += __shfl_xor(wsum, 16, 64);
  wsum += __shfl_xor(wsum, 32, 64);          // deg[d=l15], all lanes
  float dv = 1.0f / sqrtf(wsum);             // deg >= 1 (self loop)
  float Af[4];
#pragma unroll
  for (int j = 0; j < 4; ++j) {
    float dvs = __shfl(dv, 4 * lg + j, 64);  // dinv[s]
    Af[j] = wreg[j] * dv * dvs;
  }
  unsigned AH01, AL01, AH23, AL23;
  split_pk(Af[0], Af[1], AH01, AL01);
  split_pk(Af[2], Af[3], AH23, AL23);
  const s16x8 ABh = as_s16x8((u32x4){AH01, AH23, AH01, AH23});
  const s16x8 ABl = as_s16x8((u32x4){AL01, AL23, 0u, 0u});

  // --- x^T A-fragment: x[src=4lg+j][feat=l15], split hi/lo ---
  float xv[4];
#pragma unroll
  for (int j = 0; j < 4; ++j) {
    int s = 4 * lg + j;
    float v = 0.f;
    if (l15 < 8)       v = raw[s * 10 + 2 + l15];
    else if (l15 < 10) v = raw[160 + s * 2 + (l15 - 8)];
    xv[j] = v;
  }
  unsigned xH0, xL0, xH1, xL1;
  split_pk(xv[0], xv[1], xH0, xL0);
  split_pk(xv[2], xv[3], xH1, xL1);
  const s16x8 xop = as_s16x8((u32x4){xH0, xH1, xL0, xL1});

  // --- z0^T = x^T @ A : D-frag == A-frag of layer 1 (net-independent) ---
  f32x4 z0 = {0.f, 0.f, 0.f, 0.f};
  z0 = MFMA32(xop, ABh, z0);   // xh*Ah + xl*Ah
  z0 = MFMA32(xop, ABl, z0);   // xh*Al
  unsigned zH0, zL0, zH1, zL1;
  split_pk(z0[0], z0[1], zH0, zL0);
  split_pk(z0[2], z0[3], zH1, zL1);
  const s16x8 z0op = as_s16x8((u32x4){zH0, zH1, zL0, zL1});

  const s16x8* W0F = (const s16x8*)(ws + WS_W0F);
  const s16x8 zero8 = {0, 0, 0, 0, 0, 0, 0, 0};
  float b2v0 = b2a[0], b2v1 = b2b[0];

#pragma unroll 1
  for (int net = 0; net < 2; ++net) {
    const float* B0 = net ? b0b : b0a;
    const float* B1 = net ? b1b : b1a;
    const float* W2 = net ? w2b : w2a;
    const float b2v = net ? b2v1 : b2v0;

    // ---- layer 1: h1 = relu(z0@W0 + b0); D-frag -> mix A-frag, packed ----
    s16x8 h1op[8];
#pragma unroll
    for (int t = 0; t < 8; ++t) {
      s16x8 wf = W0F[(net * 8 + t) * 64 + lane];
      s16x8 Bh = __builtin_shufflevector(wf, wf, 0, 1, 2, 3, 0, 1, 2, 3);
      s16x8 Bl = __builtin_shufflevector(wf, zero8, 4, 5, 6, 7, 8, 9, 10, 11);
      float bv = B0[16 * t + l15];
      f32x4 a = {0.f, 0.f, 0.f, 0.f};
      a = MFMA32(z0op, Bh, a);
      a = MFMA32(z0op, Bl, a);
      float a0 = fmaxf(a[0] + bv, 0.f), a1 = fmaxf(a[1] + bv, 0.f);
      float a2 = fmaxf(a[2] + bv, 0.f), a3 = fmaxf(a[3] + bv, 0.f);
      unsigned H0, L0, H1, L1;
      split_pk(a0, a1, H0, L0);
      split_pk(a2, a3, H1, L1);
      h1op[t] = as_s16x8((u32x4){H0, H1, L0, L1});
    }

    // ---- mix: z1^T_t = h1_t^T @ A ; D-frag -> layer-2 A-frag, packed ----
    unsigned zHw[8][2], zLw[8][2];
#pragma unroll
    for (int t = 0; t < 8; ++t) {
      f32x4 z = {0.f, 0.f, 0.f, 0.f};
      z = MFMA32(h1op[t], ABh, z);
      z = MFMA32(h1op[t], ABl, z);
      split_pk(z[0], z[1], zHw[t][0], zLw[t][0]);
      split_pk(z[2], z[3], zHw[t][1], zLw[t][1]);
    }

    // ---- layer 2: h2 = relu(z1@W1 + b1); W1 single bf16, z split hi+lo ----
    f32x4 acc[8];
#pragma unroll
    for (int t = 0; t < 8; ++t) acc[t] = (f32x4){0.f, 0.f, 0.f, 0.f};
    __builtin_amdgcn_s_setprio(1);
#pragma unroll
    for (int q = 0; q < 4; ++q) {
      s16x8 zh8 = as_s16x8(
          (u32x4){zHw[2 * q][0], zHw[2 * q][1], zHw[2 * q + 1][0], zHw[2 * q + 1][1]});
      s16x8 zl8 = as_s16x8(
          (u32x4){zLw[2 * q][0], zLw[2 * q][1], zLw[2 * q + 1][0], zLw[2 * q + 1][1]});
      int base = (net * 4 + q) * 8 * 64 + lane;
#pragma unroll
      for (int t = 0; t < 8; ++t) {
        s16x8 W = lW[base + t * 64];
        acc[t] = MFMA32(zh8, W, acc[t]);
        acc[t] = MFMA32(zl8, W, acc[t]);
      }
    }
    __builtin_amdgcn_s_setprio(0);

    // ---- layer 3: s[node] = sum_c relu(h2+b1)*W2 ; q = A@s + b2 ----
    float part[4] = {0.f, 0.f, 0.f, 0.f};
#pragma unroll
    for (int t = 0; t < 8; ++t) {
      float bv  = B1[16 * t + l15];
      float wv2 = W2[16 * t + l15];
#pragma unroll
      for (int r = 0; r < 4; ++r)
        part[r] += fmaxf(acc[t][r] + bv, 0.f) * wv2;
    }
#pragma unroll
    for (int d = 1; d < 16; d <<= 1)
#pragma unroll
      for (int r = 0; r < 4; ++r)
        part[r] += __shfl_xor(part[r], d, 64);
    // part[j] = s[node=4lg+j] (all l15). q[d=l15] = sum_s A[l15][s]*s[s]
    float pq = Af[0] * part[0] + Af[1] * part[1] + Af[2] * part[2] + Af[3] * part[3];
    pq += __shfl_xor(pq, 16, 64);
    pq += __shfl_xor(pq, 32, 64);
    if (lane < 16)
      out[net * 65536 + batch * 16 + l15] = pq + b2v;
  }
}

extern "C" void kernel_launch(void* const* d_in, const int* in_sizes, int n_in,
                              void* d_out, int out_size, void* d_ws, size_t ws_size,
                              hipStream_t stream) {
  (void)in_sizes; (void)n_in; (void)out_size; (void)ws_size;
  const float* obs = (const float*)d_in[0];
  const float* act = (const float*)d_in[1];
  const float* w0a = (const float*)d_in[2];
  const float* b0a = (const float*)d_in[3];
  const float* w1a = (const float*)d_in[4];
  const float* b1a = (const float*)d_in[5];
  const float* w2a = (const float*)d_in[6];
  const float* b2a = (const float*)d_in[7];
  const float* w0b = (const float*)d_in[8];
  const float* b0b = (const float*)d_in[9];
  const float* w1b = (const float*)d_in[10];
  const float* b1b = (const float*)d_in[11];
  const float* w2b = (const float*)d_in[12];
  const float* b2b = (const float*)d_in[13];
  unsigned short* ws = (unsigned short*)d_ws;

  prep_weights<<<17, 256, 0, stream>>>(w0a, w1a, w0b, w1b, ws);
  gcnn_critic_kernel<<<512, 512, SMEM_TOTAL, stream>>>(
      obs, act, b0a, b1a, w2a, b2a, b0b, b1b, w2b, b2b, ws, (float*)d_out);
}